// Round 9
// baseline (626.720 us; speedup 1.0000x reference)
//
#include <hip/hip_runtime.h>
#include <math.h>

#define BDIM 8
#define MDIM 1024
#define CDIM 768
#define ROWS (BDIM * MDIM)   // 8192

typedef __attribute__((ext_vector_type(8))) short short8;   // 8 bf16
typedef __attribute__((ext_vector_type(8))) unsigned short ushort8;
typedef __attribute__((ext_vector_type(4))) float f32x4;

#define MFMA16(a, b, c) __builtin_amdgcn_mfma_f32_16x16x32_bf16((a), (b), (c), 0, 0, 0)

__device__ __forceinline__ unsigned short f2bf(float f) {
  unsigned u = __float_as_uint(f);
  return (unsigned short)((u + 0x7FFFu + ((u >> 16) & 1u)) >> 16);
}

// ---------------------------------------------------------------------------
// Prologue (one launch): input converts + weight transpose-converts +
// rowsum zeroing. Flat grid of 10184 blocks x 256 threads.
// ---------------------------------------------------------------------------
__global__ __launch_bounds__(256) void prologue(
    const float* __restrict__ xl, const float* __restrict__ xt,
    unsigned short* __restrict__ dxl, unsigned short* __restrict__ dxt,
    const float* __restrict__ W0, const float* __restrict__ W1,
    const float* __restrict__ W2, const float* __restrict__ W3,
    unsigned short* __restrict__ D0, unsigned short* __restrict__ D1,
    unsigned short* __restrict__ D2, unsigned short* __restrict__ D3,
    float* __restrict__ rowsum) {
  const int bx = blockIdx.x;
  const int tid = threadIdx.x;
  if (bx < 6144) {
    const float* src = bx < 3072 ? xl : xt;
    unsigned short* dst = bx < 3072 ? dxl : dxt;
    const int i = ((bx < 3072 ? bx : bx - 3072) * 256 + tid) * 8;
    const float4 a = *(const float4*)(src + i);
    const float4 b = *(const float4*)(src + i + 4);
    ushort8 o;
    o[0] = f2bf(a.x); o[1] = f2bf(a.y); o[2] = f2bf(a.z); o[3] = f2bf(a.w);
    o[4] = f2bf(b.x); o[5] = f2bf(b.y); o[6] = f2bf(b.z); o[7] = f2bf(b.w);
    *(ushort8*)(dst + i) = o;
  } else if (bx < 6152) {
    const int i = ((bx - 6144) * 256 + tid) * 8;
    const float4 z = {0.f, 0.f, 0.f, 0.f};
    *(float4*)(rowsum + i) = z;
    *(float4*)(rowsum + i + 4) = z;
  } else {
    int x = bx - 6152;
    int bxx = x % 168;
    const int k0 = (x / 168) * 32;
    const float* W; unsigned short* D; int N;
    if (bxx < 72)       { W = W0; D = D0; N = 2304; }
    else if (bxx < 96)  { W = W1; D = D1; N = 768;  bxx -= 72; }
    else if (bxx < 144) { W = W2; D = D2; N = 1536; bxx -= 96; }
    else                { W = W3; D = D3; N = 768;  bxx -= 144; }
    __shared__ unsigned short t[32][33];
    const int tx = tid & 31, ty = tid >> 5;
    const int n0 = bxx * 32;
#pragma unroll
    for (int i = 0; i < 4; ++i)
      t[ty + i * 8][tx] = f2bf(W[(size_t)(k0 + ty + i * 8) * N + n0 + tx]);
    __syncthreads();
#pragma unroll
    for (int i = 0; i < 4; ++i)
      D[(size_t)(n0 + ty + i * 8) * CDIM + k0 + tx] = t[tx][ty + i * 8];
  }
}

// ---------------------------------------------------------------------------
// Barrier-free MFMA K-loop: no LDS. Each lane loads its A/B fragments
// directly global->VGPR (dwordx4; a quad-group's 16 lanes hit 16 distinct
// 64B lines, fully consumed), double-buffered across 32-wide K-steps.
// No __syncthreads -> compiler emits fine-grained vmcnt waits only on frag
// use; loads stay in flight across MFMA (the AITER-style pipeline the
// 2-barrier LDS structure cannot express). Panels are L2-hot (XCD swizzle).
// ---------------------------------------------------------------------------
__device__ __forceinline__ void mfma_stream(
    const unsigned short* __restrict__ A, int lda,
    const unsigned short* __restrict__ Bt, int ldb, int K,
    f32x4 acc[4][4], int wave, int lane) {
  const int wx = wave & 1, wy = wave >> 1;
  const int quad = lane >> 4, l16 = lane & 15;
  const unsigned short* pa[4];
  const unsigned short* pb[4];
#pragma unroll
  for (int mt = 0; mt < 4; ++mt)
    pa[mt] = A + (size_t)(wy * 64 + mt * 16 + l16) * lda + quad * 8;
#pragma unroll
  for (int nt = 0; nt < 4; ++nt)
    pb[nt] = Bt + (size_t)(wx * 64 + nt * 16 + l16) * ldb + quad * 8;

  short8 a0[4], b0[4], a1[4], b1[4];
#pragma unroll
  for (int i = 0; i < 4; ++i) {
    a0[i] = *(const short8*)(pa[i]);
    b0[i] = *(const short8*)(pb[i]);
  }
  for (int k0 = 0; k0 < K; k0 += 64) {
#pragma unroll
    for (int i = 0; i < 4; ++i) {
      a1[i] = *(const short8*)(pa[i] + k0 + 32);
      b1[i] = *(const short8*)(pb[i] + k0 + 32);
    }
#pragma unroll
    for (int mt = 0; mt < 4; ++mt)
#pragma unroll
      for (int nt = 0; nt < 4; ++nt)
        acc[mt][nt] = MFMA16(a0[mt], b0[nt], acc[mt][nt]);
    if (k0 + 64 < K) {
#pragma unroll
      for (int i = 0; i < 4; ++i) {
        a0[i] = *(const short8*)(pa[i] + k0 + 64);
        b0[i] = *(const short8*)(pb[i] + k0 + 64);
      }
    }
#pragma unroll
    for (int mt = 0; mt < 4; ++mt)
#pragma unroll
      for (int nt = 0; nt < 4; ++nt)
        acc[mt][nt] = MFMA16(a1[mt], b1[nt], acc[mt][nt]);
  }
}

// Projection epilogue: slice-routed bf16 write; optional transposed write of
// the last 768-slice into vTd[b][d][n].
__device__ __forceinline__ void proj_epilogue(
    f32x4 acc[4][4], const float* __restrict__ bias,
    unsigned short* __restrict__ Y, unsigned short* __restrict__ vTd,
    int c0, int m0, int lastSlice, int trans, int wave, int lane) {
  const int wx = wave & 1, wy = wave >> 1;
  const int quad = lane >> 4, l16 = lane & 15;
  const int slice = c0 / 768;
  if (trans && slice == lastSlice) {
#pragma unroll
    for (int mt = 0; mt < 4; ++mt) {
      const int row0 = m0 + wy * 64 + mt * 16 + quad * 4;
      const int b = row0 >> 10, n0 = row0 & 1023;
#pragma unroll
      for (int nt = 0; nt < 4; ++nt) {
        const int gcol = c0 + wx * 64 + nt * 16 + l16;
        const int d = gcol - slice * 768;
        const float bv = bias[gcol];
        uint2 o;
        o.x = (unsigned)f2bf(acc[mt][nt][0] + bv) |
              ((unsigned)f2bf(acc[mt][nt][1] + bv) << 16);
        o.y = (unsigned)f2bf(acc[mt][nt][2] + bv) |
              ((unsigned)f2bf(acc[mt][nt][3] + bv) << 16);
        *(uint2*)&vTd[((size_t)b * CDIM + d) * MDIM + n0] = o;
      }
    }
  } else {
    const size_t sbase = (size_t)slice * ROWS * 768;
#pragma unroll
    for (int mt = 0; mt < 4; ++mt)
#pragma unroll
      for (int nt = 0; nt < 4; ++nt) {
        const int gcol = c0 + wx * 64 + nt * 16 + l16;
        const int lcol = gcol - slice * 768;
        const float bv = bias[gcol];
#pragma unroll
        for (int rg = 0; rg < 4; ++rg) {
          const int row = m0 + wy * 64 + mt * 16 + quad * 4 + rg;
          Y[sbase + (size_t)row * 768 + lcol] = f2bf(acc[mt][nt][rg] + bv);
        }
      }
  }
}

// XCD-swizzled block mapping: lin%8 picks the XCD; each XCD covers 8
// m-panels x all c-tiles -> A panels L2-resident per XCD.
__device__ __forceinline__ void swizzle_mc(int lin, int* m0, int* c0) {
  const int xcd = lin & 7, j = lin >> 3;
  *m0 = (xcd * 8 + (j & 7)) * 128;
  *c0 = (j >> 3) * 128;
}

// ---------------------------------------------------------------------------
// qkv projection: grid (18, 64). Q,K -> Y slices 0,1; V -> vTd transposed.
// ---------------------------------------------------------------------------
__global__ __launch_bounds__(256, 3) void gemm_proj(
    const unsigned short* __restrict__ A, const unsigned short* __restrict__ Bt,
    const float* __restrict__ bias, unsigned short* __restrict__ Y,
    unsigned short* __restrict__ vTd, int trans) {
  int m0, c0;
  swizzle_mc(blockIdx.y * gridDim.x + blockIdx.x, &m0, &c0);
  const int tid = threadIdx.x;
  const int wave = tid >> 6, lane = tid & 63;
  const f32x4 vzero = {0.f, 0.f, 0.f, 0.f};
  f32x4 acc[4][4];
#pragma unroll
  for (int mt = 0; mt < 4; ++mt)
#pragma unroll
    for (int nt = 0; nt < 4; ++nt) acc[mt][nt] = vzero;
  mfma_stream(A + (size_t)m0 * CDIM, CDIM, Bt + (size_t)c0 * CDIM, CDIM, CDIM,
              acc, wave, lane);
  proj_epilogue(acc, bias, Y, vTd, c0, m0, (int)(gridDim.x / 6) - 1, trans,
                wave, lane);
}

// ---------------------------------------------------------------------------
// Dual projection (cq + kv) in one launch: flat grid 384 + 768 = 1152.
// ---------------------------------------------------------------------------
__global__ __launch_bounds__(256, 3) void gemm_proj_dual(
    const unsigned short* __restrict__ A0, const unsigned short* __restrict__ B0,
    const float* __restrict__ b0, unsigned short* __restrict__ Y0,
    const unsigned short* __restrict__ A1, const unsigned short* __restrict__ B1,
    const float* __restrict__ b1, unsigned short* __restrict__ Y1,
    unsigned short* __restrict__ vTd) {
  int lin = blockIdx.x;
  const unsigned short *A, *Bt;
  const float* bias;
  unsigned short* Y;
  int gx, trans;
  if (lin < 384) { A = A0; Bt = B0; bias = b0; Y = Y0; gx = 6;  trans = 0; }
  else { lin -= 384; A = A1; Bt = B1; bias = b1; Y = Y1; gx = 12; trans = 1; }
  int m0, c0;
  swizzle_mc(lin, &m0, &c0);
  const int tid = threadIdx.x;
  const int wave = tid >> 6, lane = tid & 63;
  const f32x4 vzero = {0.f, 0.f, 0.f, 0.f};
  f32x4 acc[4][4];
#pragma unroll
  for (int mt = 0; mt < 4; ++mt)
#pragma unroll
    for (int nt = 0; nt < 4; ++nt) acc[mt][nt] = vzero;
  mfma_stream(A + (size_t)m0 * CDIM, CDIM, Bt + (size_t)c0 * CDIM, CDIM, CDIM,
              acc, wave, lane);
  proj_epilogue(acc, bias, Y, vTd, c0, m0, gx / 6 - 1, trans, wave, lane);
}

// ---------------------------------------------------------------------------
// FFN GEMM, f32 out: grid (6, 64), N=768.
// ---------------------------------------------------------------------------
__global__ __launch_bounds__(256, 3) void gemm_ffn(
    const unsigned short* __restrict__ A, const unsigned short* __restrict__ Bt,
    const float* __restrict__ bias, float* __restrict__ Y) {
  int m0, c0;
  swizzle_mc(blockIdx.y * gridDim.x + blockIdx.x, &m0, &c0);
  const int tid = threadIdx.x;
  const int wave = tid >> 6, lane = tid & 63;
  const int wx = wave & 1, wy = wave >> 1;
  const int quad = lane >> 4, l16 = lane & 15;
  const f32x4 vzero = {0.f, 0.f, 0.f, 0.f};
  f32x4 acc[4][4];
#pragma unroll
  for (int mt = 0; mt < 4; ++mt)
#pragma unroll
    for (int nt = 0; nt < 4; ++nt) acc[mt][nt] = vzero;
  mfma_stream(A + (size_t)m0 * CDIM, CDIM, Bt + (size_t)c0 * CDIM, CDIM, CDIM,
              acc, wave, lane);
#pragma unroll
  for (int mt = 0; mt < 4; ++mt)
#pragma unroll
    for (int nt = 0; nt < 4; ++nt) {
      const int col = c0 + wx * 64 + nt * 16 + l16;
      const float bv = bias[col];
#pragma unroll
      for (int rg = 0; rg < 4; ++rg) {
        const int row = m0 + wy * 64 + mt * 16 + quad * 4 + rg;
        Y[(size_t)row * 768 + col] = acc[mt][nt][rg] + bv;
      }
    }
}

// ---------------------------------------------------------------------------
// Batched QK^T with fused exp + row-sum (as R7). grid (8,8,BDIM).
// ---------------------------------------------------------------------------
__global__ __launch_bounds__(256, 3) void gemm_qk(
    const unsigned short* __restrict__ Qb, const unsigned short* __restrict__ Kb,
    const float* __restrict__ mask, unsigned short* __restrict__ S, float scale,
    float* __restrict__ rowsum) {
  const int c0 = blockIdx.x * 128;
  const int m0 = blockIdx.y * 128;
  const int b = blockIdx.z;
  const int tid = threadIdx.x;
  const int wave = tid >> 6, lane = tid & 63;
  const int wx = wave & 1, wy = wave >> 1;
  const int quad = lane >> 4, l16 = lane & 15;

  const f32x4 vzero = {0.f, 0.f, 0.f, 0.f};
  f32x4 acc[4][4];
#pragma unroll
  for (int mt = 0; mt < 4; ++mt)
#pragma unroll
    for (int nt = 0; nt < 4; ++nt) acc[mt][nt] = vzero;

  mfma_stream(Qb + ((size_t)b * MDIM + m0) * CDIM, CDIM,
              Kb + ((size_t)b * MDIM + c0) * CDIM, CDIM, CDIM,
              acc, wave, lane);

  const float* maskb = mask + b * MDIM;
  float mrow[4][4], rsum[4][4];
#pragma unroll
  for (int mt = 0; mt < 4; ++mt)
#pragma unroll
    for (int rg = 0; rg < 4; ++rg) {
      mrow[mt][rg] = maskb[m0 + wy * 64 + mt * 16 + quad * 4 + rg];
      rsum[mt][rg] = 0.f;
    }
  unsigned short* Sb = S + (size_t)b * MDIM * MDIM;
#pragma unroll
  for (int nt = 0; nt < 4; ++nt) {
    const int col = c0 + wx * 64 + nt * 16 + l16;
    const float mcol = maskb[col];
#pragma unroll
    for (int mt = 0; mt < 4; ++mt)
#pragma unroll
      for (int rg = 0; rg < 4; ++rg) {
        const int row = m0 + wy * 64 + mt * 16 + quad * 4 + rg;
        const float e = (mrow[mt][rg] * mcol != 0.f)
                            ? __expf(acc[mt][nt][rg] * scale)
                            : 1e-30f;
        Sb[(size_t)row * MDIM + col] = f2bf(e);
        rsum[mt][rg] += e;
      }
  }
  for (int off = 1; off < 16; off <<= 1) {
#pragma unroll
    for (int mt = 0; mt < 4; ++mt)
#pragma unroll
      for (int rg = 0; rg < 4; ++rg)
        rsum[mt][rg] += __shfl_xor(rsum[mt][rg], off, 64);
  }
  if (l16 == 0) {
    float* rsb = rowsum + (b << 10) + m0 + wy * 64;
#pragma unroll
    for (int mt = 0; mt < 4; ++mt)
#pragma unroll
      for (int rg = 0; rg < 4; ++rg)
        atomicAdd(&rsb[mt * 16 + quad * 4 + rg], rsum[mt][rg]);
  }
}

// ---------------------------------------------------------------------------
// O = (unnormalized P) @ V, normalized by 1/rowsum per row. grid (6,8,BDIM).
// ---------------------------------------------------------------------------
__global__ __launch_bounds__(256, 3) void attn_pv(
    const unsigned short* __restrict__ P, const unsigned short* __restrict__ vT,
    unsigned short* __restrict__ O, const float* __restrict__ rowsum) {
  const int c0 = blockIdx.x * 128;
  const int m0 = blockIdx.y * 128;
  const int b = blockIdx.z;
  const int tid = threadIdx.x;
  const int wave = tid >> 6, lane = tid & 63;
  const int wx = wave & 1, wy = wave >> 1;
  const int quad = lane >> 4, l16 = lane & 15;

  const f32x4 vzero = {0.f, 0.f, 0.f, 0.f};
  f32x4 acc[4][4];
#pragma unroll
  for (int mt = 0; mt < 4; ++mt)
#pragma unroll
    for (int nt = 0; nt < 4; ++nt) acc[mt][nt] = vzero;

  mfma_stream(P + ((size_t)b * MDIM + m0) * MDIM, MDIM,
              vT + ((size_t)b * CDIM + c0) * MDIM, MDIM, MDIM,
              acc, wave, lane);

  const float* rsb = rowsum + (b << 10) + m0 + wy * 64;
  float inv[4][4];
#pragma unroll
  for (int mt = 0; mt < 4; ++mt)
#pragma unroll
    for (int rg = 0; rg < 4; ++rg)
      inv[mt][rg] = 1.f / rsb[mt * 16 + quad * 4 + rg];
#pragma unroll
  for (int mt = 0; mt < 4; ++mt)
#pragma unroll
    for (int nt = 0; nt < 4; ++nt)
#pragma unroll
      for (int rg = 0; rg < 4; ++rg) {
        const int row = m0 + wy * 64 + mt * 16 + quad * 4 + rg;
        const int col = c0 + wx * 64 + nt * 16 + l16;
        O[(size_t)(b * MDIM + row) * CDIM + col] =
            f2bf(acc[mt][nt][rg] * inv[mt][rg]);
      }
}

// ---------------------------------------------------------------------------
extern "C" void kernel_launch(void* const* d_in, const int* in_sizes, int n_in,
                              void* d_out, int out_size, void* d_ws, size_t ws_size,
                              hipStream_t stream) {
  const float* layout_x = (const float*)d_in[0];
  const float* text_x   = (const float*)d_in[1];
  const float* maskp    = (const float*)d_in[2];
  const float* Wqkv     = (const float*)d_in[3];
  const float* bqkv     = (const float*)d_in[4];
  const float* Wq       = (const float*)d_in[5];
  const float* bq       = (const float*)d_in[6];
  const float* Wkv      = (const float*)d_in[7];
  const float* bkv      = (const float*)d_in[8];
  const float* Wffn     = (const float*)d_in[9];
  const float* bffn     = (const float*)d_in[10];
  float* out = (float*)d_out;
  char* ws = (char*)d_ws;

  const float scale = 1.0f / sqrtf((float)CDIM);

  // ---- workspace (bytes), total 100,532,224 (same as R7) ----
  unsigned short* xlb    = (unsigned short*)(ws);              // -> attn1/merge
  unsigned short* xtb    = (unsigned short*)(ws + 12582912);
  unsigned short* Wqkv_t = (unsigned short*)(ws + 25165824);
  unsigned short* Wq_t   = (unsigned short*)(ws + 28704768);
  unsigned short* Wkv_t  = (unsigned short*)(ws + 29884416);
  unsigned short* Wffn_t = (unsigned short*)(ws + 32243712);
  unsigned short* Qb     = (unsigned short*)(ws + 33423360);   // slice1=K contiguous
  unsigned short* Kb     = (unsigned short*)(ws + 46006272);
  unsigned short* cqb    = (unsigned short*)(ws + 58589184);
  unsigned short* vT     = (unsigned short*)(ws + 71172096);   // V^T / cV^T
  unsigned short* S      = (unsigned short*)(ws + 83755008);
  unsigned short* attn1  = xlb;
  unsigned short* Kc     = Qb;           // Qb dead after qk1
  float* rowsum1 = out;                  // 8192 f32 (d_out head, FFN overwrites)
  float* rowsum2 = out + 8192;           // 8192 f32

  // 1) prologue
  prologue<<<10184, 256, 0, stream>>>(layout_x, text_x, xlb, xtb,
                                      Wqkv, Wq, Wkv, Wffn,
                                      Wqkv_t, Wq_t, Wkv_t, Wffn_t, rowsum1);
  // 2) Q,K -> Qb,Kb; V -> vT transposed
  gemm_proj<<<dim3(18, 64), 256, 0, stream>>>(xlb, Wqkv_t, bqkv, Qb, vT, 1);
  // 3) S = exp(scale*QK^T) masked; rowsum1 += row sums
  gemm_qk<<<dim3(8, 8, BDIM), 256, 0, stream>>>(Qb, Kb, maskp, S, scale, rowsum1);
  // 4) attn1 = bf16((S @ V) / rowsum1)
  attn_pv<<<dim3(6, 8, BDIM), 256, 0, stream>>>(S, vT, attn1, rowsum1);
  // 5) cq = attn1@Wq+bq  AND  cK,cV = xtb@Wkv+bkv (cV -> vT transposed)
  gemm_proj_dual<<<1152, 256, 0, stream>>>(attn1, Wq_t, bq, cqb,
                                           xtb, Wkv_t, bkv, Kc, vT);
  // 6) S = exp(scale*cq cK^T) masked; rowsum2 += row sums
  gemm_qk<<<dim3(8, 8, BDIM), 256, 0, stream>>>(cqb, Kc, maskp, S, scale, rowsum2);
  // 7) merge = bf16((S @ cV) / rowsum2)
  attn_pv<<<dim3(6, 8, BDIM), 256, 0, stream>>>(S, vT, attn1, rowsum2);
  // 8) out = merge @ Wffn + bffn (f32; overwrites rowsum area)
  gemm_ffn<<<dim3(6, 64), 256, 0, stream>>>(attn1, Wffn_t, bffn, out);
}

// Round 10
// 329.421 us; speedup vs baseline: 1.9025x; 1.9025x over previous
//
#include <hip/hip_runtime.h>
#include <math.h>

#define BDIM 8
#define MDIM 1024
#define CDIM 768
#define ROWS (BDIM * MDIM)   // 8192

typedef __attribute__((ext_vector_type(8))) short short8;   // 8 bf16
typedef __attribute__((ext_vector_type(8))) unsigned short ushort8;
typedef __attribute__((ext_vector_type(4))) float f32x4;

#define MFMA16(a, b, c) __builtin_amdgcn_mfma_f32_16x16x32_bf16((a), (b), (c), 0, 0, 0)

__device__ __forceinline__ unsigned short f2bf(float f) {
  unsigned u = __float_as_uint(f);
  return (unsigned short)((u + 0x7FFFu + ((u >> 16) & 1u)) >> 16);
}
__device__ __forceinline__ float bf2f(unsigned short b) {
  return __uint_as_float(((unsigned)b) << 16);
}

// ---------------------------------------------------------------------------
// Prologue (one launch): input converts + weight transposes + rowsum zeroing
// + per-batch mask compaction (permutation p: raw->compact, idx: compact->raw,
// unmasked first). Grid 10192 x 256.
// ---------------------------------------------------------------------------
__global__ __launch_bounds__(256) void prologue(
    const float* __restrict__ xl, const float* __restrict__ xt,
    unsigned short* __restrict__ dxl, unsigned short* __restrict__ dxt,
    const float* __restrict__ W0, const float* __restrict__ W1,
    const float* __restrict__ W2, const float* __restrict__ W3,
    unsigned short* __restrict__ D0, unsigned short* __restrict__ D1,
    unsigned short* __restrict__ D2, unsigned short* __restrict__ D3,
    const float* __restrict__ mask, float* __restrict__ rowsum,
    unsigned short* __restrict__ idxArr, unsigned short* __restrict__ pArr,
    int* __restrict__ nuArr) {
  const int bx = blockIdx.x;
  const int tid = threadIdx.x;
  if (bx < 6144) {
    const float* src = bx < 3072 ? xl : xt;
    unsigned short* dst = bx < 3072 ? dxl : dxt;
    const int i = ((bx < 3072 ? bx : bx - 3072) * 256 + tid) * 8;
    const float4 a = *(const float4*)(src + i);
    const float4 b = *(const float4*)(src + i + 4);
    ushort8 o;
    o[0] = f2bf(a.x); o[1] = f2bf(a.y); o[2] = f2bf(a.z); o[3] = f2bf(a.w);
    o[4] = f2bf(b.x); o[5] = f2bf(b.y); o[6] = f2bf(b.z); o[7] = f2bf(b.w);
    *(ushort8*)(dst + i) = o;
  } else if (bx < 6152) {
    const int i = ((bx - 6144) * 256 + tid) * 8;
    const float4 z = {0.f, 0.f, 0.f, 0.f};
    *(float4*)(rowsum + i) = z;
    *(float4*)(rowsum + i + 4) = z;
  } else if (bx < 10184) {
    int x = bx - 6152;
    int bxx = x % 168;
    const int k0 = (x / 168) * 32;
    const float* W; unsigned short* D; int N;
    if (bxx < 72)       { W = W0; D = D0; N = 2304; }
    else if (bxx < 96)  { W = W1; D = D1; N = 768;  bxx -= 72; }
    else if (bxx < 144) { W = W2; D = D2; N = 1536; bxx -= 96; }
    else                { W = W3; D = D3; N = 768;  bxx -= 144; }
    __shared__ unsigned short t[32][33];
    const int tx = tid & 31, ty = tid >> 5;
    const int n0 = bxx * 32;
#pragma unroll
    for (int i = 0; i < 4; ++i)
      t[ty + i * 8][tx] = f2bf(W[(size_t)(k0 + ty + i * 8) * N + n0 + tx]);
    __syncthreads();
#pragma unroll
    for (int i = 0; i < 4; ++i)
      D[(size_t)(n0 + ty + i * 8) * CDIM + k0 + tx] = t[tx][ty + i * 8];
  } else {
    // per-batch compaction, one wave
    const int b = bx - 10184;
    if (tid >= 64) return;
    const unsigned long long below = (1ull << tid) - 1ull;
    const float* mb = mask + (b << 10);
    unsigned long long bals[16];
    int nu = 0;
#pragma unroll
    for (int c = 0; c < 16; ++c) {
      const float mv = mb[c * 64 + tid];
      bals[c] = __ballot(mv != 0.f);
      nu += (int)__popcll(bals[c]);
    }
    int ru = 0, rm = 0;
#pragma unroll
    for (int c = 0; c < 16; ++c) {
      const unsigned long long bal = bals[c];
      const int preU = (int)__popcll(bal & below);
      const int preM = tid - preU;
      const int m = c * 64 + tid;
      const int pos = ((bal >> tid) & 1ull) ? (ru + preU) : (nu + rm + preM);
      pArr[(b << 10) + m] = (unsigned short)pos;
      idxArr[(b << 10) + pos] = (unsigned short)m;
      const int tot = (int)__popcll(bal);
      ru += tot; rm += 64 - tot;
    }
    if (tid == 0) nuArr[b] = nu;
  }
}

// ---------------------------------------------------------------------------
// BK=64 MFMA engine (R7, proven): XOR-swizzled 128x64 LDS tiles, async
// global_load_lds width=16, conflict-free frag reads.
// ---------------------------------------------------------------------------
__device__ __forceinline__ void stage64(
    const unsigned short* __restrict__ g, int ld, int k0,
    unsigned short* lds, int wave, int lane) {
  const int gchunk = (lane & 7) ^ (lane >> 3);
#pragma unroll
  for (int j = 0; j < 4; ++j) {
    const int grp = wave * 4 + j;
    const unsigned short* gp =
        g + (size_t)(grp * 8 + (lane >> 3)) * ld + k0 + gchunk * 8;
    __builtin_amdgcn_global_load_lds(
        (const __attribute__((address_space(1))) unsigned int*)gp,
        (__attribute__((address_space(3))) unsigned int*)(lds + grp * 512),
        16, 0, 0);
  }
}

__device__ __forceinline__ void mfma_loop64(
    const unsigned short* __restrict__ A, int lda,
    const unsigned short* __restrict__ Bt, int ldb, int K,
    unsigned short* As, unsigned short* Bs, f32x4 acc[4][4],
    int wave, int lane) {
  const int wx = wave & 1, wy = wave >> 1;
  const int quad = lane >> 4, l16 = lane & 15;
  for (int k0 = 0; k0 < K; k0 += 64) {
    stage64(A, lda, k0, As, wave, lane);
    stage64(Bt, ldb, k0, Bs, wave, lane);
    __syncthreads();
#pragma unroll
    for (int h = 0; h < 2; ++h) {
      const int slot = ((((h << 2) | quad) ^ (l16 & 7))) * 8;
      short8 afr[4], bfr[4];
#pragma unroll
      for (int mt = 0; mt < 4; ++mt)
        afr[mt] = *(const short8*)&As[(wy * 64 + mt * 16 + l16) * 64 + slot];
#pragma unroll
      for (int nt = 0; nt < 4; ++nt)
        bfr[nt] = *(const short8*)&Bs[(wx * 64 + nt * 16 + l16) * 64 + slot];
#pragma unroll
      for (int mt = 0; mt < 4; ++mt)
#pragma unroll
        for (int nt = 0; nt < 4; ++nt)
          acc[mt][nt] = MFMA16(afr[mt], bfr[nt], acc[mt][nt]);
    }
    __syncthreads();
  }
}

// Projection epilogue: slice-routed bf16 write with optional row permutation
// (raw row -> batch-local compact position p) and optional transposed+
// column-permuted write of the LAST slice into vTd[b][d][p[n]].
__device__ __forceinline__ void proj_epilogue(
    f32x4 acc[4][4], const float* __restrict__ bias,
    unsigned short* __restrict__ Y, unsigned short* __restrict__ vTd,
    const unsigned short* __restrict__ pArr,
    int c0, int m0, int lastSlice, int trans, int perm, int wave, int lane) {
  const int wx = wave & 1, wy = wave >> 1;
  const int quad = lane >> 4, l16 = lane & 15;
  const int slice = c0 / 768;
  if (trans && slice == lastSlice) {
#pragma unroll
    for (int mt = 0; mt < 4; ++mt) {
      const int row0 = m0 + wy * 64 + mt * 16 + quad * 4;
      const int b = row0 >> 10;
#pragma unroll
      for (int nt = 0; nt < 4; ++nt) {
        const int gcol = c0 + wx * 64 + nt * 16 + l16;
        const int d = gcol - slice * 768;
        const float bv = bias[gcol];
#pragma unroll
        for (int rg = 0; rg < 4; ++rg) {
          const int pos = pArr[row0 + rg];
          vTd[((size_t)b * CDIM + d) * MDIM + pos] = f2bf(acc[mt][nt][rg] + bv);
        }
      }
    }
  } else {
    const size_t sbase = (size_t)slice * ROWS * 768;
#pragma unroll
    for (int mt = 0; mt < 4; ++mt)
#pragma unroll
      for (int nt = 0; nt < 4; ++nt) {
        const int gcol = c0 + wx * 64 + nt * 16 + l16;
        const int lcol = gcol - slice * 768;
        const float bv = bias[gcol];
#pragma unroll
        for (int rg = 0; rg < 4; ++rg) {
          const int row = m0 + wy * 64 + mt * 16 + quad * 4 + rg;
          const int orow = perm ? ((row & ~1023) + (int)pArr[row]) : row;
          Y[sbase + (size_t)orow * 768 + lcol] = f2bf(acc[mt][nt][rg] + bv);
        }
      }
  }
}

// XCD-swizzled block mapping: lin%8 picks the XCD; each XCD covers 8
// m-panels x all c-tiles -> A panels L2-resident per XCD.
__device__ __forceinline__ void swizzle_mc(int lin, int* m0, int* c0) {
  const int xcd = lin & 7, j = lin >> 3;
  *m0 = (xcd * 8 + (j & 7)) * 128;
  *c0 = (j >> 3) * 128;
}

// ---------------------------------------------------------------------------
// qkv projection: grid (18, 64). Q,K -> slices 0,1 row-permuted; V -> vTd
// transposed + column-permuted.
// ---------------------------------------------------------------------------
__global__ __launch_bounds__(256, 4) void gemm_proj(
    const unsigned short* __restrict__ A, const unsigned short* __restrict__ Bt,
    const float* __restrict__ bias, unsigned short* __restrict__ Y,
    unsigned short* __restrict__ vTd, const unsigned short* __restrict__ pArr) {
  __shared__ __align__(16) unsigned short As[128 * 64];
  __shared__ __align__(16) unsigned short Bs[128 * 64];
  int m0, c0;
  swizzle_mc(blockIdx.y * gridDim.x + blockIdx.x, &m0, &c0);
  const int tid = threadIdx.x;
  const int wave = tid >> 6, lane = tid & 63;
  const f32x4 vzero = {0.f, 0.f, 0.f, 0.f};
  f32x4 acc[4][4];
#pragma unroll
  for (int mt = 0; mt < 4; ++mt)
#pragma unroll
    for (int nt = 0; nt < 4; ++nt) acc[mt][nt] = vzero;
  mfma_loop64(A + (size_t)m0 * CDIM, CDIM, Bt + (size_t)c0 * CDIM, CDIM, CDIM,
              As, Bs, acc, wave, lane);
  proj_epilogue(acc, bias, Y, vTd, pArr, c0, m0, (int)(gridDim.x / 6) - 1,
                1, 1, wave, lane);
}

// ---------------------------------------------------------------------------
// Dual projection: cq (compact rows in = compact rows out, no perm) + kv
// (cK row-permuted, cV transposed+col-permuted). Flat grid 384 + 768.
// ---------------------------------------------------------------------------
__global__ __launch_bounds__(256, 4) void gemm_proj_dual(
    const unsigned short* __restrict__ A0, const unsigned short* __restrict__ B0,
    const float* __restrict__ b0, unsigned short* __restrict__ Y0,
    const unsigned short* __restrict__ A1, const unsigned short* __restrict__ B1,
    const float* __restrict__ b1, unsigned short* __restrict__ Y1,
    unsigned short* __restrict__ vTd, const unsigned short* __restrict__ pArr) {
  __shared__ __align__(16) unsigned short As[128 * 64];
  __shared__ __align__(16) unsigned short Bs[128 * 64];
  int lin = blockIdx.x;
  const unsigned short *A, *Bt;
  const float* bias;
  unsigned short* Y;
  int lastSlice, trans, perm;
  if (lin < 384) { A = A0; Bt = B0; bias = b0; Y = Y0; lastSlice = 0; trans = 0; perm = 0; }
  else { lin -= 384; A = A1; Bt = B1; bias = b1; Y = Y1; lastSlice = 1; trans = 1; perm = 1; }
  int m0, c0;
  swizzle_mc(lin, &m0, &c0);
  const int tid = threadIdx.x;
  const int wave = tid >> 6, lane = tid & 63;
  const f32x4 vzero = {0.f, 0.f, 0.f, 0.f};
  f32x4 acc[4][4];
#pragma unroll
  for (int mt = 0; mt < 4; ++mt)
#pragma unroll
    for (int nt = 0; nt < 4; ++nt) acc[mt][nt] = vzero;
  mfma_loop64(A + (size_t)m0 * CDIM, CDIM, Bt + (size_t)c0 * CDIM, CDIM, CDIM,
              As, Bs, acc, wave, lane);
  proj_epilogue(acc, bias, Y, vTd, pArr, c0, m0, lastSlice, trans, perm,
                wave, lane);
}

// ---------------------------------------------------------------------------
// FFN GEMM, f32 out: grid (6, 64). Reads full raw merge.
// ---------------------------------------------------------------------------
__global__ __launch_bounds__(256, 4) void gemm_ffn(
    const unsigned short* __restrict__ A, const unsigned short* __restrict__ Bt,
    const float* __restrict__ bias, float* __restrict__ Y) {
  __shared__ __align__(16) unsigned short As[128 * 64];
  __shared__ __align__(16) unsigned short Bs[128 * 64];
  int m0, c0;
  swizzle_mc(blockIdx.y * gridDim.x + blockIdx.x, &m0, &c0);
  const int tid = threadIdx.x;
  const int wave = tid >> 6, lane = tid & 63;
  const int wx = wave & 1, wy = wave >> 1;
  const int quad = lane >> 4, l16 = lane & 15;
  const f32x4 vzero = {0.f, 0.f, 0.f, 0.f};
  f32x4 acc[4][4];
#pragma unroll
  for (int mt = 0; mt < 4; ++mt)
#pragma unroll
    for (int nt = 0; nt < 4; ++nt) acc[mt][nt] = vzero;
  mfma_loop64(A + (size_t)m0 * CDIM, CDIM, Bt + (size_t)c0 * CDIM, CDIM, CDIM,
              As, Bs, acc, wave, lane);
#pragma unroll
  for (int mt = 0; mt < 4; ++mt)
#pragma unroll
    for (int nt = 0; nt < 4; ++nt) {
      const int col = c0 + wx * 64 + nt * 16 + l16;
      const float bv = bias[col];
#pragma unroll
      for (int rg = 0; rg < 4; ++rg) {
        const int row = m0 + wy * 64 + mt * 16 + quad * 4 + rg;
        Y[(size_t)row * 768 + col] = acc[mt][nt][rg] + bv;
      }
    }
}

// ---------------------------------------------------------------------------
// Compact QK^T + fused exp + row-sum: inputs are row-permuted Q,K (unmasked
// in [0,nu)). Tiles beyond nuPad exit; e gated to the compact-valid square.
// S compact, stride 1024. grid (8,8,BDIM).
// ---------------------------------------------------------------------------
__global__ __launch_bounds__(256, 4) void gemm_qk(
    const unsigned short* __restrict__ Qc, const unsigned short* __restrict__ Kc,
    unsigned short* __restrict__ S, float scale, float* __restrict__ rowsum,
    const int* __restrict__ nuArr) {
  __shared__ __align__(16) unsigned short As[128 * 64];
  __shared__ __align__(16) unsigned short Bs[128 * 64];
  const int b = blockIdx.z;
  const int nu = nuArr[b];
  const int nuPad = (nu + 127) & ~127;
  const int c0 = blockIdx.x * 128;
  const int m0 = blockIdx.y * 128;
  if (m0 >= nuPad || c0 >= nuPad) return;
  const int tid = threadIdx.x;
  const int wave = tid >> 6, lane = tid & 63;
  const int wx = wave & 1, wy = wave >> 1;
  const int quad = lane >> 4, l16 = lane & 15;

  const f32x4 vzero = {0.f, 0.f, 0.f, 0.f};
  f32x4 acc[4][4];
#pragma unroll
  for (int mt = 0; mt < 4; ++mt)
#pragma unroll
    for (int nt = 0; nt < 4; ++nt) acc[mt][nt] = vzero;

  mfma_loop64(Qc + ((size_t)(b << 10) + m0) * CDIM, CDIM,
              Kc + ((size_t)(b << 10) + c0) * CDIM, CDIM, CDIM,
              As, Bs, acc, wave, lane);

  float rsum[4][4];
#pragma unroll
  for (int mt = 0; mt < 4; ++mt)
#pragma unroll
    for (int rg = 0; rg < 4; ++rg) rsum[mt][rg] = 0.f;
  unsigned short* Sb = S + ((size_t)b << 20);
#pragma unroll
  for (int nt = 0; nt < 4; ++nt) {
    const int col = c0 + wx * 64 + nt * 16 + l16;
    const int cv = col < nu;
#pragma unroll
    for (int mt = 0; mt < 4; ++mt)
#pragma unroll
      for (int rg = 0; rg < 4; ++rg) {
        const int i = m0 + wy * 64 + mt * 16 + quad * 4 + rg;
        const float e = (i < nu && cv) ? __expf(acc[mt][nt][rg] * scale) : 0.f;
        Sb[(size_t)i * MDIM + col] = f2bf(e);
        rsum[mt][rg] += e;
      }
  }
  for (int off = 1; off < 16; off <<= 1) {
#pragma unroll
    for (int mt = 0; mt < 4; ++mt)
#pragma unroll
      for (int rg = 0; rg < 4; ++rg)
        rsum[mt][rg] += __shfl_xor(rsum[mt][rg], off, 64);
  }
  if (l16 == 0) {
    float* rsb = rowsum + (b << 10) + m0 + wy * 64;
#pragma unroll
    for (int mt = 0; mt < 4; ++mt)
#pragma unroll
      for (int rg = 0; rg < 4; ++rg)
        atomicAdd(&rsb[mt * 16 + quad * 4 + rg], rsum[mt][rg]);
  }
}

// ---------------------------------------------------------------------------
// O = (compact P) @ (permuted V), normalized per row. SCATTER: write rows
// back to raw positions via idx (guarded i<nu); else compact rows.
// grid (6,8,BDIM).
// ---------------------------------------------------------------------------
template <bool SCATTER>
__global__ __launch_bounds__(256, 4) void attn_pv(
    const unsigned short* __restrict__ S, const unsigned short* __restrict__ vTc,
    unsigned short* __restrict__ O, const float* __restrict__ rowsum,
    const int* __restrict__ nuArr, const unsigned short* __restrict__ idxArr) {
  __shared__ __align__(16) unsigned short As[128 * 64];
  __shared__ __align__(16) unsigned short Bs[128 * 64];
  const int b = blockIdx.z;
  const int nu = nuArr[b];
  const int m0 = blockIdx.y * 128;
  if (m0 >= ((nu + 127) & ~127)) return;
  const int kmax = (nu + 63) & ~63;
  const int c0 = blockIdx.x * 128;
  const int tid = threadIdx.x;
  const int wave = tid >> 6, lane = tid & 63;
  const int wx = wave & 1, wy = wave >> 1;
  const int quad = lane >> 4, l16 = lane & 15;

  const f32x4 vzero = {0.f, 0.f, 0.f, 0.f};
  f32x4 acc[4][4];
#pragma unroll
  for (int mt = 0; mt < 4; ++mt)
#pragma unroll
    for (int nt = 0; nt < 4; ++nt) acc[mt][nt] = vzero;

  mfma_loop64(S + ((size_t)b << 20) + (size_t)m0 * MDIM, MDIM,
              vTc + ((size_t)b * CDIM + c0) * MDIM, MDIM, kmax,
              As, Bs, acc, wave, lane);

  const float* rsb = rowsum + (b << 10) + m0 + wy * 64;
  float inv[4][4];
#pragma unroll
  for (int mt = 0; mt < 4; ++mt)
#pragma unroll
    for (int rg = 0; rg < 4; ++rg)
      inv[mt][rg] = 1.f / rsb[mt * 16 + quad * 4 + rg];
#pragma unroll
  for (int mt = 0; mt < 4; ++mt)
#pragma unroll
    for (int nt = 0; nt < 4; ++nt)
#pragma unroll
      for (int rg = 0; rg < 4; ++rg) {
        const int i = m0 + wy * 64 + mt * 16 + quad * 4 + rg;
        const int col = c0 + wx * 64 + nt * 16 + l16;
        if (SCATTER) {
          if (i < nu) {
            const int m = idxArr[(b << 10) + i];
            O[((size_t)(b << 10) + m) * CDIM + col] =
                f2bf(acc[mt][nt][rg] * inv[mt][rg]);
          }
        } else {
          O[((size_t)(b << 10) + i) * CDIM + col] =
              f2bf(acc[mt][nt][rg] * inv[mt][rg]);
        }
      }
}

// ---------------------------------------------------------------------------
// meanCV[b][d] = mean over all 1024 (permuted = all raw) columns of cvTc.
// grid 6144, block 256.
// ---------------------------------------------------------------------------
__global__ __launch_bounds__(256) void mean_cols(
    const unsigned short* __restrict__ vTc, float* __restrict__ meanCV) {
  const unsigned short* p = vTc + (size_t)blockIdx.x * MDIM;
  const int t = threadIdx.x;
  const int wave = t >> 6, lane = t & 63;
  __shared__ float red[4];
  const uint2 u = *(const uint2*)(p + t * 4);
  float s = bf2f((unsigned short)(u.x & 0xFFFFu)) +
            bf2f((unsigned short)(u.x >> 16)) +
            bf2f((unsigned short)(u.y & 0xFFFFu)) +
            bf2f((unsigned short)(u.y >> 16));
  for (int off = 1; off < 64; off <<= 1) s += __shfl_xor(s, off, 64);
  if (lane == 0) red[wave] = s;
  __syncthreads();
  if (t == 0)
    meanCV[blockIdx.x] = (red[0] + red[1] + red[2] + red[3]) * (1.f / 1024.f);
}

// ---------------------------------------------------------------------------
// Fill masked raw rows of merge with bf16(meanCV[b]). grid ROWS, block 256.
// ---------------------------------------------------------------------------
__global__ __launch_bounds__(256) void fill_masked(
    const float* __restrict__ mask, const float* __restrict__ meanCV,
    unsigned short* __restrict__ merge) {
  const int m = blockIdx.x;
  if (mask[m] != 0.f) return;
  const float* mv = meanCV + (m >> 10) * CDIM;
  unsigned short* o = merge + (size_t)m * CDIM;
  const int t = threadIdx.x;
  o[t] = f2bf(mv[t]);
  o[t + 256] = f2bf(mv[t + 256]);
  o[t + 512] = f2bf(mv[t + 512]);
}

// ---------------------------------------------------------------------------
extern "C" void kernel_launch(void* const* d_in, const int* in_sizes, int n_in,
                              void* d_out, int out_size, void* d_ws, size_t ws_size,
                              hipStream_t stream) {
  const float* layout_x = (const float*)d_in[0];
  const float* text_x   = (const float*)d_in[1];
  const float* maskp    = (const float*)d_in[2];
  const float* Wqkv     = (const float*)d_in[3];
  const float* bqkv     = (const float*)d_in[4];
  const float* Wq       = (const float*)d_in[5];
  const float* bq       = (const float*)d_in[6];
  const float* Wkv      = (const float*)d_in[7];
  const float* bkv      = (const float*)d_in[8];
  const float* Wffn     = (const float*)d_in[9];
  const float* bffn     = (const float*)d_in[10];
  float* out = (float*)d_out;
  char* ws = (char*)d_ws;

  const float scale = 1.0f / sqrtf((float)CDIM);

  // ---- workspace (bytes), total 100,532,224 (same as R7) ----
  unsigned short* xlb    = (unsigned short*)(ws);              // -> attn1c/merge
  unsigned short* xtb    = (unsigned short*)(ws + 12582912);
  unsigned short* Wqkv_t = (unsigned short*)(ws + 25165824);
  unsigned short* Wq_t   = (unsigned short*)(ws + 28704768);
  unsigned short* Wkv_t  = (unsigned short*)(ws + 29884416);
  unsigned short* Wffn_t = (unsigned short*)(ws + 32243712);
  unsigned short* Qc     = (unsigned short*)(ws + 33423360);   // perm Q -> cKc
  unsigned short* Kc     = (unsigned short*)(ws + 46006272);   // perm K
  unsigned short* cqc    = (unsigned short*)(ws + 58589184);
  unsigned short* vTc    = (unsigned short*)(ws + 71172096);   // perm V^T / cV^T
  unsigned short* S      = (unsigned short*)(ws + 83755008);
  unsigned short* attn1c = xlb;          // compact rows, dead after dual
  unsigned short* merge  = xlb;          // raw rows (fill + pv2-scatter)
  unsigned short* cKc    = Qc;           // Qc dead after qk1

  // ---- d_out head scratch (all consumed before FFN writes d_out) ----
  float* rowsum1 = out;                           // [0,8192)
  float* rowsum2 = out + 8192;                    // [8192,16384)
  unsigned short* idxArr = (unsigned short*)(out + 16384);  // 8192 ushort
  unsigned short* pArr   = (unsigned short*)(out + 20480);  // 8192 ushort
  int* nuArr             = (int*)(out + 24576);             // 8 int
  float* meanCV          = out + 24592;                     // 6144 f32

  // 1) prologue: converts + weight transposes + rowsum zero + compaction
  prologue<<<10192, 256, 0, stream>>>(layout_x, text_x, xlb, xtb,
                                      Wqkv, Wq, Wkv, Wffn,
                                      Wqkv_t, Wq_t, Wkv_t, Wffn_t,
                                      maskp, rowsum1, idxArr, pArr, nuArr);
  // 2) Q,K row-permuted -> Qc,Kc; V -> vTc transposed+col-permuted
  gemm_proj<<<dim3(18, 64), 256, 0, stream>>>(xlb, Wqkv_t, bqkv, Qc, vTc, pArr);
  // 3) S = exp(scale*QcKc^T) on compact square; rowsum1 += sums
  gemm_qk<<<dim3(8, 8, BDIM), 256, 0, stream>>>(Qc, Kc, S, scale, rowsum1, nuArr);
  // 4) attn1c = bf16((S @ Vc) / rowsum1), compact rows
  attn_pv<false><<<dim3(6, 8, BDIM), 256, 0, stream>>>(S, vTc, attn1c, rowsum1,
                                                       nuArr, idxArr);
  // 5) cqc = attn1c@Wq+bq (compact); cK perm -> cKc; cV -> vTc trans+perm
  gemm_proj_dual<<<1152, 256, 0, stream>>>(attn1c, Wq_t, bq, cqc,
                                           xtb, Wkv_t, bkv, cKc, vTc, pArr);
  // 6) meanCV = column means of cvTc (all raw n)
  mean_cols<<<6144, 256, 0, stream>>>(vTc, meanCV);
  // 7) masked raw rows of merge = bf16(meanCV)
  fill_masked<<<ROWS, 256, 0, stream>>>(maskp, meanCV, merge);
  // 8) S = exp(scale*cqc cKc^T) compact; rowsum2 += sums
  gemm_qk<<<dim3(8, 8, BDIM), 256, 0, stream>>>(cqc, cKc, S, scale, rowsum2, nuArr);
  // 9) unmasked raw rows of merge = bf16((S @ cVc)/rowsum2), scattered via idx
  attn_pv<true><<<dim3(6, 8, BDIM), 256, 0, stream>>>(S, vTc, merge, rowsum2,
                                                      nuArr, idxArr);
  // 10) out = merge @ Wffn + bffn (f32)
  gemm_ffn<<<dim3(6, 64), 256, 0, stream>>>(merge, Wffn_t, bffn, out);
}